// Round 10
// baseline (813.366 us; speedup 1.0000x reference)
//
#include <hip/hip_runtime.h>
#include <math.h>

// InstantNGP-style hash-grid encoder, 16 levels, FEAT=2, B=2M points.
//   dense levels 0..4 (res^3 <= 2^19), hashed levels 5..15 (size = 2^19 each)
//
// Measured cost law (r3-r9): fully-divergent gathers cost ~127 cyc per
// wave-instruction per CU at <=8B/lane (~1.5x at 16B), independent of cache
// level, active-lane mask, and payload width below 8B. Fine kernels (8x 8B
// gathers/pt from the pristine f32 table + 8B NT ws store) sit at this floor:
// 51.6us/level. r9 lesson: LDS staging cut occupancy to 43% and regressed.
// Structure:
//   - convert_quad_kernel: dense quad table Q[j] = bf16x2 {T[j], T[j+1],
//     T[j+res], T[j+res+1]} (mod size) -> 4 corners per 16B gather.
//   - 11x fine_level_kernel -> fws slices (proven config, untouched).
//   - dense_merge_kernel (no LDS): 5 dense levels at 2x 16B gathers each,
//     merge 11 fws slices, write [B,32] directly. Streaming overlaps TA.
#define NLEVELS 16
#define BEGIN_FAST 5
#define P2 2654435761u
#define P3 805459861u
#define FAST_MASK 524287u
#define DENSE_TOTAL 330952u

constexpr unsigned kRes[NLEVELS] = {16u, 23u, 31u, 43u, 59u, 81u, 112u, 154u, 213u, 295u, 407u, 562u, 777u, 1073u, 1483u, 2048u};
constexpr unsigned kSize[NLEVELS] = {
    4096u, 12168u, 29792u, 79512u, 205384u,
    524288u, 524288u, 524288u, 524288u, 524288u, 524288u,
    524288u, 524288u, 524288u, 524288u, 524288u};
constexpr unsigned kOffset[NLEVELS] = {
    0u,       4096u,    16264u,   46056u,   125568u,  330952u,
    855240u,  1379528u, 1903816u, 2428104u, 2952392u, 3476680u,
    4000968u, 4525256u, 5049544u, 5573832u};

struct Scales {
    float s[NLEVELS];
};

typedef float fvec2 __attribute__((ext_vector_type(2)));
typedef float fvec4 __attribute__((ext_vector_type(4)));
typedef unsigned uvec4 __attribute__((ext_vector_type(4)));

// pack two f32 -> bf16x2 (round-to-nearest-even), lo = a, hi = b
__device__ __forceinline__ unsigned bfpack(float a, float b) {
    unsigned ua = __float_as_uint(a);
    unsigned ub = __float_as_uint(b);
    ua = (ua + 0x7FFFu + ((ua >> 16) & 1u)) >> 16;
    ub = (ub + 0x7FFFu + ((ub >> 16) & 1u)) & 0xFFFF0000u;
    return ua | ub;
}
__device__ __forceinline__ float bf_lo(unsigned e) { return __uint_as_float(e << 16); }
__device__ __forceinline__ float bf_hi(unsigned e) { return __uint_as_float(e & 0xFFFF0000u); }

// ---- dense quad table: Q[j] = bf16x2 of T[j], T[j+1], T[j+res], T[j+res+1] --
__global__ __launch_bounds__(256) void convert_quad_kernel(
    const float2* __restrict__ table,  // full f32 table
    uvec4* __restrict__ Q,             // quad bf16 dense table [DENSE_TOTAL]
    int total)
{
    int j = blockIdx.x * 256 + threadIdx.x;
    if (j >= total) return;
    int l = 0;
    if (j >= (int)kOffset[1]) l = 1;
    if (j >= (int)kOffset[2]) l = 2;
    if (j >= (int)kOffset[3]) l = 3;
    if (j >= (int)kOffset[4]) l = 4;
    const unsigned size = kSize[l];
    const unsigned res = kRes[l];
    const unsigned jl = (unsigned)j - kOffset[l];
    unsigned j1 = jl + 1u;        if (j1 >= size) j1 -= size;
    unsigned jy = jl + res;       if (jy >= size) jy -= size;
    unsigned jy1 = jy + 1u;       if (jy1 >= size) jy1 -= size;
    const float2 t0 = table[kOffset[l] + jl];
    const float2 t1 = table[kOffset[l] + j1];
    const float2 t2 = table[kOffset[l] + jy];
    const float2 t3 = table[kOffset[l] + jy1];
    uvec4 r = {bfpack(t0.x, t0.y), bfpack(t1.x, t1.y),
               bfpack(t2.x, t2.y), bfpack(t3.x, t3.y)};
    __builtin_nontemporal_store(r, Q + j);
}

// ---------------- fine (hashed) level: EXACT proven 51.6us config ------------
__global__ __launch_bounds__(256) void fine_level_kernel(
    const float* __restrict__ positions,  // [B,3]
    const float2* __restrict__ tab,       // f32 table + level offset
    float2* __restrict__ wsl,             // ws slice [B], float2
    int B, float s)
{
    int p = blockIdx.x * 256 + threadIdx.x;
    if (p >= B) return;

    const float x = __builtin_nontemporal_load(positions + 3 * p + 0);
    const float y = __builtin_nontemporal_load(positions + 3 * p + 1);
    const float z = __builtin_nontemporal_load(positions + 3 * p + 2);

    const float px = x * s + 0.5f;
    const float py = y * s + 0.5f;
    const float pz = z * s + 0.5f;
    const float flx = floorf(px), fly = floorf(py), flz = floorf(pz);
    const float rx = px - flx, ry = py - fly, rz = pz - flz;
    const unsigned gx = (unsigned)flx;
    const unsigned gy = (unsigned)fly;
    const unsigned gz = (unsigned)flz;
    const float wx0 = 1.0f - rx, wy0 = 1.0f - ry, wz0 = 1.0f - rz;

    const unsigned hy0 = gy * P2, hy1 = hy0 + P2;
    const unsigned hz0 = gz * P3, hz1 = hz0 + P3;

    float ax = 0.0f, ay = 0.0f;
#pragma unroll
    for (int c = 0; c < 8; ++c) {
        const unsigned cx = (unsigned)(c & 1);
        const unsigned cy = (unsigned)((c >> 1) & 1);
        const unsigned cz = (unsigned)((c >> 2) & 1);
        const float w = (cx ? rx : wx0) * (cy ? ry : wy0) * (cz ? rz : wz0);
        const unsigned h = (gx + cx) ^ (cy ? hy1 : hy0) ^ (cz ? hz1 : hz0);
        const float2 t = tab[h & FAST_MASK];
        ax += w * t.x;
        ay += w * t.y;
    }
    fvec2 r = {ax, ay};
    __builtin_nontemporal_store(r, reinterpret_cast<fvec2*>(wsl) + p);
}

// ---- dense levels via quad table (2x 16B/level) + merge fws -> output -------
__global__ __launch_bounds__(256) void dense_merge_kernel(
    const float* __restrict__ positions,  // [B,3]
    const uvec4* __restrict__ Q,          // quad bf16 dense table
    const float2* __restrict__ fws,       // [11][B] fine slices
    float* __restrict__ out,              // [B,32]
    int B, Scales sc)
{
    const int p = blockIdx.x * 256 + threadIdx.x;
    if (p >= B) return;

    const float x = __builtin_nontemporal_load(positions + 3 * p + 0);
    const float y = __builtin_nontemporal_load(positions + 3 * p + 1);
    const float z = __builtin_nontemporal_load(positions + 3 * p + 2);

    float o[2 * NLEVELS];

#pragma unroll
    for (int l = 0; l < BEGIN_FAST; ++l) {
        const float s = sc.s[l];
        const float px = x * s + 0.5f;
        const float py = y * s + 0.5f;
        const float pz = z * s + 0.5f;
        const float flx = floorf(px), fly = floorf(py), flz = floorf(pz);
        const float rx = px - flx, ry = py - fly, rz = pz - flz;
        const unsigned gx = (unsigned)flx;
        const unsigned gy = (unsigned)fly;
        const unsigned gz = (unsigned)flz;
        const float wx0 = 1.0f - rx, wy0 = 1.0f - ry, wz0 = 1.0f - rz;

        const uvec4* tabQ = Q + kOffset[l];
        const unsigned res = kRes[l];
        const unsigned res2 = res * res;
        const unsigned h0 = gx + gy * res + gz * res2;

        float ax = 0.0f, ay = 0.0f;
#pragma unroll
        for (int cz = 0; cz < 2; ++cz) {
            const float wz = cz ? rz : wz0;
            const unsigned idx = (h0 + (unsigned)cz * res2) % kSize[l];
            const uvec4 q = tabQ[idx];   // 16B gather: 4 (cx,cy) corners
            ax += wz * (wy0 * (wx0 * bf_lo(q.x) + rx * bf_lo(q.y)) +
                        ry  * (wx0 * bf_lo(q.z) + rx * bf_lo(q.w)));
            ay += wz * (wy0 * (wx0 * bf_hi(q.x) + rx * bf_hi(q.y)) +
                        ry  * (wx0 * bf_hi(q.z) + rx * bf_hi(q.w)));
        }
        o[2 * l + 0] = ax;
        o[2 * l + 1] = ay;
    }

#pragma unroll
    for (int l = BEGIN_FAST; l < NLEVELS; ++l) {
        const fvec2 v = __builtin_nontemporal_load(
            reinterpret_cast<const fvec2*>(fws) + (size_t)(l - BEGIN_FAST) * (size_t)B + p);
        o[2 * l + 0] = v.x;
        o[2 * l + 1] = v.y;
    }

    float* op = out + (size_t)p * (2 * NLEVELS);
#pragma unroll
    for (int i = 0; i < 8; ++i) {
        fvec4 v = {o[4 * i + 0], o[4 * i + 1], o[4 * i + 2], o[4 * i + 3]};
        *(reinterpret_cast<fvec4*>(op) + i) = v;
    }
}

// ---------------- fallback: monolithic f32 (if ws too small) -----------------
__global__ __launch_bounds__(256) void hash_encode_kernel(
    const float* __restrict__ positions,
    const float2* __restrict__ table,
    float* __restrict__ out,
    int B, Scales sc)
{
    int p = blockIdx.x * 256 + threadIdx.x;
    if (p >= B) return;

    const float x = positions[3 * p + 0];
    const float y = positions[3 * p + 1];
    const float z = positions[3 * p + 2];

    float o[2 * NLEVELS];

#pragma unroll
    for (int l = 0; l < NLEVELS; ++l) {
        const float s = sc.s[l];
        const float px = x * s + 0.5f;
        const float py = y * s + 0.5f;
        const float pz = z * s + 0.5f;
        const float flx = floorf(px), fly = floorf(py), flz = floorf(pz);
        const float rx = px - flx, ry = py - fly, rz = pz - flz;
        const unsigned gx = (unsigned)flx;
        const unsigned gy = (unsigned)fly;
        const unsigned gz = (unsigned)flz;
        const float wx0 = 1.0f - rx, wy0 = 1.0f - ry, wz0 = 1.0f - rz;

        float ax = 0.0f, ay = 0.0f;
#pragma unroll
        for (int c = 0; c < 8; ++c) {
            const unsigned cx = (unsigned)(c & 1);
            const unsigned cy = (unsigned)((c >> 1) & 1);
            const unsigned cz = (unsigned)((c >> 2) & 1);
            const unsigned pgx = gx + cx;
            const unsigned pgy = gy + cy;
            const unsigned pgz = gz + cz;
            const float w = (cx ? rx : wx0) * (cy ? ry : wy0) * (cz ? rz : wz0);
            unsigned h;
            if (l < BEGIN_FAST) {
                h = pgx + pgy * kRes[l] + pgz * (kRes[l] * kRes[l]);
            } else {
                h = pgx ^ (pgy * P2) ^ (pgz * P3);
            }
            const unsigned idx = (h % kSize[l]) + kOffset[l];
            const float2 t = table[idx];
            ax += w * t.x;
            ay += w * t.y;
        }
        o[2 * l + 0] = ax;
        o[2 * l + 1] = ay;
    }

    float* op = out + (size_t)p * (2 * NLEVELS);
#pragma unroll
    for (int i = 0; i < 8; ++i) {
        fvec4 v = {o[4 * i + 0], o[4 * i + 1], o[4 * i + 2], o[4 * i + 3]};
        *(reinterpret_cast<fvec4*>(op) + i) = v;
    }
}

extern "C" void kernel_launch(void* const* d_in, const int* in_sizes, int n_in,
                              void* d_out, int out_size, void* d_ws, size_t ws_size,
                              hipStream_t stream) {
    const float* positions = (const float*)d_in[0];
    const float2* table = (const float2*)d_in[1];
    float* out = (float*)d_out;

    const int B = in_sizes[0] / 3;

    Scales sc;
    const double log_b = log(2048.0 / 16.0) / (NLEVELS - 1);
    for (int l = 0; l < NLEVELS; ++l) {
        sc.s[l] = (float)(16.0 * exp((double)l * log_b) - 1.0);
    }

    const int blocks = (B + 255) / 256;

    // ws layout: [11 fine slices, 8B each][quad dense table Q, 16B each]
    const size_t fws_bytes = 11u * (size_t)B * sizeof(float2);        // 176 MB
    const size_t Q_bytes = (size_t)DENSE_TOTAL * sizeof(uvec4);       // 5.3 MB
    const size_t ws_need = fws_bytes + Q_bytes;

    if (ws_size >= ws_need) {
        float2* fws = (float2*)d_ws;
        uvec4* Q = (uvec4*)((char*)d_ws + fws_bytes);

        convert_quad_kernel<<<((int)DENSE_TOTAL + 255) / 256, 256, 0, stream>>>(
            table, Q, (int)DENSE_TOTAL);

        for (int l = BEGIN_FAST; l < NLEVELS; ++l) {
            fine_level_kernel<<<blocks, 256, 0, stream>>>(
                positions, table + kOffset[l],
                fws + (size_t)(l - BEGIN_FAST) * (size_t)B, B, sc.s[l]);
        }
        dense_merge_kernel<<<blocks, 256, 0, stream>>>(positions, Q, fws, out, B, sc);
    } else {
        hash_encode_kernel<<<blocks, 256, 0, stream>>>(positions, table, out, B, sc);
    }
}